// Round 8
// baseline (298.310 us; speedup 1.0000x reference)
//
#include <hip/hip_runtime.h>
#include <cstdint>

#define BB 2
#define NN 16384
#define MM 4096
#define CF 256
#define CT 128
#define CP 64
#define CFT (CF + CT)   // 384 transposed channels
#define NPB 64          // query points per block (grid 512 — keeps FETCH low)
#define CHUNK 2048      // ref points staged in LDS per pass (32 KB)
#define TPB 512

// ---------------------------------------------------------------------------
// K1: transpose refF[b][c][m] ++ refT[b][c][m]  ->  FT[b][m][c]  (c = 0..383)
// so phase-2 gathers become contiguous per-neighbor rows of 384 floats.
// ---------------------------------------------------------------------------
__global__ __launch_bounds__(256) void transpose_kernel(
    const float* __restrict__ refF, const float* __restrict__ refT,
    float* __restrict__ FT)
{
    __shared__ float tile[32][33];
    const int b  = blockIdx.z;
    const int m0 = blockIdx.x * 32;
    const int c0 = blockIdx.y * 32;   // multiple of 32; 256-boundary never split
    const int tx = threadIdx.x & 31;
    const int ty = threadIdx.x >> 5;  // 0..7
    #pragma unroll
    for (int k = 0; k < 4; ++k) {
        const int c = c0 + ty + k * 8;
        const float* row = (c < CF) ? (refF + ((size_t)b * CF + c) * MM)
                                    : (refT + ((size_t)b * CT + (c - CF)) * MM);
        tile[ty + k * 8][tx] = row[m0 + tx];          // coalesced along m
    }
    __syncthreads();
    #pragma unroll
    for (int k = 0; k < 4; ++k) {
        const int m = m0 + ty + k * 8;
        FT[((size_t)b * MM + m) * CFT + c0 + tx] = tile[tx][ty + k * 8]; // coalesced along c
    }
}

// ---------------------------------------------------------------------------
// K2: exact 3-NN (numpy fp32: contraction off, numpy association order,
// stable lower-index tie-break). 16 groups x 32 lanes; each group owns 4
// points (P=4/lane) so one ds_read_b128 serves 4 (point,ref) pairs.
// P=4 merge structure correctness-verified in round 6 (passed, absmax 0.0156).
// ---------------------------------------------------------------------------
__global__ __launch_bounds__(TPB, 4) void knn_kernel(
    const float* __restrict__ coords,      // [B,N,3]
    const float* __restrict__ ref_coords,  // [B,M,3]
    int* __restrict__ idx_ws,              // [B*N*3]
    float* __restrict__ w_ws)              // [B*N*3]
{
#pragma clang fp contract(off)
    __shared__ float4 refs[CHUNK];         // 32 KB (x, y, z, rr)

    const int tid = threadIdx.x;
    const int b   = blockIdx.y;
    const int n0  = blockIdx.x * NPB;

    const int h = tid >> 5;                // group 0..15 (owns 4 points)
    const int s = tid & 31;                // lane within group

    float cx[4], cy[4], cz[4], cc[4];
    {
        const float* cbase = coords + ((size_t)b * NN + n0 + h * 4) * 3;
        #pragma unroll
        for (int p = 0; p < 4; ++p) {
            const float x = cbase[p * 3 + 0];
            const float y = cbase[p * 3 + 1];
            const float z = cbase[p * 3 + 2];
            cx[p] = x; cy[p] = y; cz[p] = z;
            cc[p] = (x * x + y * y) + z * z;   // numpy sum order
        }
    }

    float d0[4], d1[4], d2[4];
    int   i0[4], i1[4], i2[4];
    #pragma unroll
    for (int p = 0; p < 4; ++p) {
        d0[p] = INFINITY; d1[p] = INFINITY; d2[p] = INFINITY;
        i0[p] = 0; i1[p] = 0; i2[p] = 0;       // benign fallbacks
    }

    const float* rc = ref_coords + (size_t)b * MM * 3;

    for (int ch = 0; ch < MM / CHUNK; ++ch) {
        __syncthreads();
        for (int e = tid; e < CHUNK; e += TPB) {
            const int j = ch * CHUNK + e;
            const float x = rc[3 * j + 0];
            const float y = rc[3 * j + 1];
            const float z = rc[3 * j + 2];
            refs[e] = make_float4(x, y, z, (x * x + y * y) + z * z);
        }
        __syncthreads();

        // lane scans e = s, s+32, ... ascending -> strict '<' keeps lowest idx
        for (int it = 0; it < CHUNK / 32; ++it) {
            const int e = s + (it << 5);
            const float4 r = refs[e];
            const int j = ch * CHUNK + e;
            #pragma unroll
            for (int p = 0; p < 4; ++p) {
                const float t  = (cx[p] * r.x + cy[p] * r.y) + cz[p] * r.z;
                const float dd = (cc[p] + r.w) - (t + t);    // (A+B)-2*dot
                const bool l2 = dd < d2[p];
                const bool l1 = dd < d1[p];
                const bool l0 = dd < d0[p];
                d2[p] = l2 ? (l1 ? d1[p] : dd) : d2[p];  i2[p] = l2 ? (l1 ? i1[p] : j) : i2[p];
                d1[p] = l1 ? (l0 ? d0[p] : dd) : d1[p];  i1[p] = l1 ? (l0 ? i0[p] : j) : i1[p];
                d0[p] = l0 ? dd : d0[p];                 i0[p] = l0 ? j : i0[p];
            }
        }
    }

    auto ins = [](float& D0, float& D1, float& D2, int& I0, int& I1, int& I2,
                  float e, int f) {
        const bool l2 = (e < D2) || (e == D2 && f < I2);
        const bool l1 = (e < D1) || (e == D1 && f < I1);
        const bool l0 = (e < D0) || (e == D0 && f < I0);
        D2 = l2 ? (l1 ? D1 : e) : D2;  I2 = l2 ? (l1 ? I1 : f) : I2;
        D1 = l1 ? (l0 ? D0 : e) : D1;  I1 = l1 ? (l0 ? I0 : f) : I1;
        D0 = l0 ? e : D0;              I0 = l0 ? f : I0;
    };

    for (int off = 1; off < 32; off <<= 1) {
        #pragma unroll
        for (int p = 0; p < 4; ++p) {
            const float e0 = __shfl_xor(d0[p], off, 64);
            const float e1 = __shfl_xor(d1[p], off, 64);
            const float e2 = __shfl_xor(d2[p], off, 64);
            const int   f0 = __shfl_xor(i0[p], off, 64);
            const int   f1 = __shfl_xor(i1[p], off, 64);
            const int   f2 = __shfl_xor(i2[p], off, 64);
            ins(d0[p], d1[p], d2[p], i0[p], i1[p], i2[p], e0, f0);
            ins(d0[p], d1[p], d2[p], i0[p], i1[p], i2[p], e1, f1);
            ins(d0[p], d1[p], d2[p], i0[p], i1[p], i2[p], e2, f2);
        }
    }

    if (s == 0) {
        #pragma unroll
        for (int p = 0; p < 4; ++p) {
            float w0 = 1.0f / (d0[p] + 1e-8f);     // IEEE divs, numpy order
            float w1 = 1.0f / (d1[p] + 1e-8f);
            float w2 = 1.0f / (d2[p] + 1e-8f);
            const float sum = (w0 + w1) + w2;
            const size_t q = ((size_t)b * NN + n0 + h * 4 + p) * 3;
            idx_ws[q + 0] = i0[p];
            idx_ws[q + 1] = i1[p];
            idx_ws[q + 2] = i2[p];
            w_ws[q + 0] = w0 / sum;
            w_ws[q + 1] = w1 / sum;
            w_ws[q + 2] = w2 / sum;
        }
    }
}

// ---------------------------------------------------------------------------
// K3: interpolation from transposed FT + skip-copy.
// grid.y 0..5: 64 FT channels each (float4 gathers, coalesced dword stores);
// grid.y == 6: copy the 64 points_features rows.
// ---------------------------------------------------------------------------
__global__ __launch_bounds__(256) void interp_kernel(
    const float* __restrict__ FT,          // [B][M][384]
    const float* __restrict__ pf,          // [B,64,N]
    const int* __restrict__ idx_ws,
    const float* __restrict__ w_ws,
    float* __restrict__ out)
{
#pragma clang fp contract(off)
    const int b = blockIdx.z;
    const int y = blockIdx.y;              // 0..6
    const int n = blockIdx.x * 256 + threadIdx.x;

    if (y == 6) {                          // skip concat rows 256..319
        for (int r = 0; r < CP; ++r)
            out[((size_t)b * (CF + CP) + CF + r) * NN + n] =
                pf[((size_t)b * CP + r) * NN + n];
        return;
    }

    const size_t p = (size_t)b * NN + n;
    auto clampi = [](int v) { return v < 0 ? 0 : (v > MM - 1 ? MM - 1 : v); };
    const int   i0 = clampi(idx_ws[p * 3 + 0]);
    const int   i1 = clampi(idx_ws[p * 3 + 1]);
    const int   i2 = clampi(idx_ws[p * 3 + 2]);
    const float w0 = w_ws[p * 3 + 0], w1 = w_ws[p * 3 + 1], w2 = w_ws[p * 3 + 2];

    const float* r0 = FT + ((size_t)b * MM + i0) * CFT;
    const float* r1 = FT + ((size_t)b * MM + i1) * CFT;
    const float* r2 = FT + ((size_t)b * MM + i2) * CFT;
    const size_t outT_base = (size_t)BB * (CF + CP) * NN;
    const int c0 = y * 64;

    for (int i = 0; i < 16; ++i) {
        const int c = c0 + i * 4;
        const float4 f0 = *reinterpret_cast<const float4*>(r0 + c);
        const float4 f1 = *reinterpret_cast<const float4*>(r1 + c);
        const float4 f2 = *reinterpret_cast<const float4*>(r2 + c);
        float v[4];
        v[0] = (w0 * f0.x + w1 * f1.x) + w2 * f2.x;   // einsum k-order
        v[1] = (w0 * f0.y + w1 * f1.y) + w2 * f2.y;
        v[2] = (w0 * f0.z + w1 * f1.z) + w2 * f2.z;
        v[3] = (w0 * f0.w + w1 * f1.w) + w2 * f2.w;
        #pragma unroll
        for (int q = 0; q < 4; ++q) {
            const int ch = c + q;
            float* dst = (ch < CF)
                ? (out + ((size_t)b * (CF + CP) + ch) * NN)
                : (out + outT_base + ((size_t)b * CT + (ch - CF)) * NN);
            dst[n] = v[q];                 // coalesced across lanes
        }
    }
}

// ---------------------------------------------------------------------------
// Fallback: the round-7 proven monolithic kernel (used only if ws too small).
// ---------------------------------------------------------------------------
__global__ __launch_bounds__(TPB, 4) void fp_fused_kernel(
    const float* __restrict__ coords, const float* __restrict__ ref_coords,
    const float* __restrict__ refF, const float* __restrict__ refT,
    const float* __restrict__ pf, float* __restrict__ out)
{
#pragma clang fp contract(off)
    __shared__ float4 refs[CHUNK];
    __shared__ int    s_idx[NPB * 3];
    __shared__ float  s_w[NPB * 3];

    const int tid = threadIdx.x;
    const int b   = blockIdx.y;
    const int n0  = blockIdx.x * NPB;
    const int pl = tid >> 3;
    const int s  = tid & 7;
    const int n  = n0 + pl;

    const float* cp = coords + ((size_t)b * NN + n) * 3;
    const float cx = cp[0], cy = cp[1], cz = cp[2];
    const float cc = (cx * cx + cy * cy) + cz * cz;

    float d0 = INFINITY, d1 = INFINITY, d2v = INFINITY;
    int   i0 = 0, i1 = 0, i2 = 0;
    const float* rc = ref_coords + (size_t)b * MM * 3;

    for (int ch = 0; ch < MM / CHUNK; ++ch) {
        __syncthreads();
        for (int e = tid; e < CHUNK; e += TPB) {
            const int j = ch * CHUNK + e;
            const float x = rc[3 * j + 0], y = rc[3 * j + 1], z = rc[3 * j + 2];
            refs[e] = make_float4(x, y, z, (x * x + y * y) + z * z);
        }
        __syncthreads();
        #pragma unroll 4
        for (int it = 0; it < CHUNK / 8; ++it) {
            const int e = s + (it << 3);
            const float4 r = refs[e];
            const float t  = (cx * r.x + cy * r.y) + cz * r.z;
            const float dd = (cc + r.w) - (t + t);
            const int j = ch * CHUNK + e;
            const bool l2 = dd < d2v, l1 = dd < d1, l0 = dd < d0;
            d2v = l2 ? (l1 ? d1 : dd) : d2v;  i2 = l2 ? (l1 ? i1 : j) : i2;
            d1  = l1 ? (l0 ? d0 : dd) : d1;   i1 = l1 ? (l0 ? i0 : j) : i1;
            d0  = l0 ? dd : d0;               i0 = l0 ? j  : i0;
        }
    }
    auto ins = [&](float e, int f) {
        const bool l2 = (e < d2v) || (e == d2v && f < i2);
        const bool l1 = (e < d1)  || (e == d1  && f < i1);
        const bool l0 = (e < d0)  || (e == d0  && f < i0);
        d2v = l2 ? (l1 ? d1 : e) : d2v;  i2 = l2 ? (l1 ? i1 : f) : i2;
        d1  = l1 ? (l0 ? d0 : e) : d1;   i1 = l1 ? (l0 ? i0 : f) : i1;
        d0  = l0 ? e : d0;               i0 = l0 ? f : i0;
    };
    for (int off = 1; off < 8; off <<= 1) {
        const float e0 = __shfl_xor(d0, off, 64), e1 = __shfl_xor(d1, off, 64), e2 = __shfl_xor(d2v, off, 64);
        const int   f0 = __shfl_xor(i0, off, 64), f1 = __shfl_xor(i1, off, 64), f2 = __shfl_xor(i2, off, 64);
        ins(e0, f0); ins(e1, f1); ins(e2, f2);
    }
    if (s == 0) {
        float w0 = 1.0f / (d0 + 1e-8f), w1 = 1.0f / (d1 + 1e-8f), w2 = 1.0f / (d2v + 1e-8f);
        const float sum = (w0 + w1) + w2;
        s_idx[pl * 3 + 0] = i0; s_idx[pl * 3 + 1] = i1; s_idx[pl * 3 + 2] = i2;
        s_w[pl * 3 + 0] = w0 / sum; s_w[pl * 3 + 1] = w1 / sum; s_w[pl * 3 + 2] = w2 / sum;
    }
    __syncthreads();

    const int g = tid >> 5, l = tid & 31, p0 = 2 * l;
    auto clampi = [](int v) { return v < 0 ? 0 : (v > MM - 1 ? MM - 1 : v); };
    const int ia0 = clampi(s_idx[p0 * 3 + 0]), ia1 = clampi(s_idx[p0 * 3 + 1]), ia2 = clampi(s_idx[p0 * 3 + 2]);
    const int ib0 = clampi(s_idx[p0 * 3 + 3]), ib1 = clampi(s_idx[p0 * 3 + 4]), ib2 = clampi(s_idx[p0 * 3 + 5]);
    const float wa0 = s_w[p0 * 3 + 0], wa1 = s_w[p0 * 3 + 1], wa2 = s_w[p0 * 3 + 2];
    const float wb0 = s_w[p0 * 3 + 3], wb1 = s_w[p0 * 3 + 4], wb2 = s_w[p0 * 3 + 5];
    const size_t outT_base = (size_t)BB * (CF + CP) * NN;

    for (int it = 0; it < (CF + CP + CT) / 16; ++it) {
        const int row = it * 16 + g;
        if (row < CF) {
            const float* src = refF + ((size_t)b * CF + row) * MM;
            float* dst = out + ((size_t)b * (CF + CP) + row) * NN + n0;
            float2 pr;
            pr.x = (wa0 * src[ia0] + wa1 * src[ia1]) + wa2 * src[ia2];
            pr.y = (wb0 * src[ib0] + wb1 * src[ib1]) + wb2 * src[ib2];
            *reinterpret_cast<float2*>(dst + p0) = pr;
        } else if (row < CF + CP) {
            const float* src = pf + ((size_t)b * CP + (row - CF)) * NN + n0;
            float* dst = out + ((size_t)b * (CF + CP) + row) * NN + n0;
            *reinterpret_cast<float2*>(dst + p0) = *reinterpret_cast<const float2*>(src + p0);
        } else {
            const int tr = row - (CF + CP);
            const float* src = refT + ((size_t)b * CT + tr) * MM;
            float* dst = out + outT_base + ((size_t)b * CT + tr) * NN + n0;
            float2 pr;
            pr.x = (wa0 * src[ia0] + wa1 * src[ia1]) + wa2 * src[ia2];
            pr.y = (wb0 * src[ib0] + wb1 * src[ib1]) + wb2 * src[ib2];
            *reinterpret_cast<float2*>(dst + p0) = pr;
        }
    }
}

extern "C" void kernel_launch(void* const* d_in, const int* in_sizes, int n_in,
                              void* d_out, int out_size, void* d_ws, size_t ws_size,
                              hipStream_t stream) {
    const float* coords     = (const float*)d_in[0];
    const float* ref_coords = (const float*)d_in[1];
    const float* refF       = (const float*)d_in[2];
    const float* refT       = (const float*)d_in[3];
    const float* pf         = (const float*)d_in[4];
    float* out = (float*)d_out;

    const size_t ft_bytes  = (size_t)BB * MM * CFT * sizeof(float);   // 12.6 MB
    const size_t idx_bytes = (size_t)BB * NN * 3 * sizeof(int);       // 0.39 MB
    const size_t need      = ft_bytes + 2 * idx_bytes;

    if (ws_size >= need) {
        float* FT     = (float*)d_ws;
        int*   idx_ws = (int*)((char*)d_ws + ft_bytes);
        float* w_ws   = (float*)((char*)d_ws + ft_bytes + idx_bytes);

        hipLaunchKernelGGL(transpose_kernel, dim3(MM / 32, CFT / 32, BB), dim3(256),
                           0, stream, refF, refT, FT);
        hipLaunchKernelGGL(knn_kernel, dim3(NN / NPB, BB), dim3(TPB), 0, stream,
                           coords, ref_coords, idx_ws, w_ws);
        hipLaunchKernelGGL(interp_kernel, dim3(NN / 256, 7, BB), dim3(256), 0, stream,
                           FT, pf, idx_ws, w_ws, out);
    } else {
        hipLaunchKernelGGL(fp_fused_kernel, dim3(NN / NPB, BB), dim3(TPB), 0, stream,
                           coords, ref_coords, refF, refT, pf, out);
    }
}

// Round 9
// 263.580 us; speedup vs baseline: 1.1318x; 1.1318x over previous
//
#include <hip/hip_runtime.h>
#include <cstdint>

#define BB 2
#define NN 16384
#define MM 4096
#define CF 256
#define CT 128
#define CP 64
#define NPB 64      // query points per block (grid 512 -> staging FETCH low)
#define CHUNK 2048  // ref points staged in LDS per pass (32 KB)
#define TPB 1024    // 16 waves/block x 2 blocks/CU -> 32 waves/CU (100% occ)

// All-FP32 monolithic kernel (round-7 proven structure; only the shape
// changed: TPB 512->1024, 16 sub-lanes/point, 32 phase-2 row groups).
// Phase 1: exact 3-NN — numpy-bit-exact fp32 (contraction off, numpy
// association order, stable lower-index tie-break).
// Phase 2: gather-interp + skip concat (free: overlaps inside the kernel).
__global__ __launch_bounds__(TPB, 8) void fp_fused_kernel(
    const float* __restrict__ coords,      // [B,N,3]
    const float* __restrict__ ref_coords,  // [B,M,3]
    const float* __restrict__ refF,        // [B,256,M]
    const float* __restrict__ refT,        // [B,128,M]
    const float* __restrict__ pf,          // [B,64,N]
    float* __restrict__ out)               // [B,320,N] ++ [B,128,N]
{
#pragma clang fp contract(off)
    __shared__ float4 refs[CHUNK];      // 32 KB (x, y, z, rr)
    __shared__ int    s_idx[NPB * 3];
    __shared__ float  s_w[NPB * 3];

    const int tid = threadIdx.x;
    const int b   = blockIdx.y;
    const int n0  = blockIdx.x * NPB;

    // ---------------- phase 1: 3-NN, 16 lanes per query point ---------------
    const int pl = tid >> 4;            // point-in-block 0..63
    const int s  = tid & 15;            // sub-lane 0..15
    const int n  = n0 + pl;

    const float* cp = coords + ((size_t)b * NN + n) * 3;
    const float cx = cp[0];
    const float cy = cp[1];
    const float cz = cp[2];
    const float cc = (cx * cx + cy * cy) + cz * cz;   // numpy sum order

    float d0 = INFINITY, d1 = INFINITY, d2v = INFINITY;
    int   i0 = 0, i1 = 0, i2 = 0;       // benign fallbacks (no sentinels)

    const float* rc = ref_coords + (size_t)b * MM * 3;

    for (int ch = 0; ch < MM / CHUNK; ++ch) {
        __syncthreads();                 // refs[] reuse guard
        for (int e = tid; e < CHUNK; e += TPB) {
            const int j = ch * CHUNK + e;
            const float x = rc[3 * j + 0];
            const float y = rc[3 * j + 1];
            const float z = rc[3 * j + 2];
            refs[e] = make_float4(x, y, z, (x * x + y * y) + z * z);
        }
        __syncthreads();

        // lane scans e = s, s+16, ... ascending -> strict '<' keeps lowest idx
        #pragma unroll 4
        for (int it = 0; it < CHUNK / 16; ++it) {
            const int e = s + (it << 4);
            const float4 r = refs[e];
            const float t  = (cx * r.x + cy * r.y) + cz * r.z;  // einsum order
            const float dd = (cc + r.w) - (t + t);              // (A+B)-2*dot
            const int j = ch * CHUNK + e;
            const bool l2 = dd < d2v;
            const bool l1 = dd < d1;
            const bool l0 = dd < d0;
            d2v = l2 ? (l1 ? d1 : dd) : d2v;  i2 = l2 ? (l1 ? i1 : j) : i2;
            d1  = l1 ? (l0 ? d0 : dd) : d1;   i1 = l1 ? (l0 ? i0 : j) : i1;
            d0  = l0 ? dd : d0;               i0 = l0 ? j  : i0;
        }
    }

    // lexicographic (d, idx) insert: lower index wins exact ties (stable top_k)
    auto ins = [&](float e, int f) {
        const bool l2 = (e < d2v) || (e == d2v && f < i2);
        const bool l1 = (e < d1)  || (e == d1  && f < i1);
        const bool l0 = (e < d0)  || (e == d0  && f < i0);
        d2v = l2 ? (l1 ? d1 : e) : d2v;  i2 = l2 ? (l1 ? i1 : f) : i2;
        d1  = l1 ? (l0 ? d0 : e) : d1;   i1 = l1 ? (l0 ? i0 : f) : i1;
        d0  = l0 ? e : d0;               i0 = l0 ? f : i0;
    };

    // butterfly across the 16 sub-lanes (xor<16 stays in-group, in-wave)
    for (int off = 1; off < 16; off <<= 1) {
        const float e0 = __shfl_xor(d0,  off, 64);
        const float e1 = __shfl_xor(d1,  off, 64);
        const float e2 = __shfl_xor(d2v, off, 64);
        const int   f0 = __shfl_xor(i0,  off, 64);
        const int   f1 = __shfl_xor(i1,  off, 64);
        const int   f2 = __shfl_xor(i2,  off, 64);
        ins(e0, f0);
        ins(e1, f1);
        ins(e2, f2);
    }

    if (s == 0) {
        float w0 = 1.0f / (d0  + 1e-8f);     // IEEE divs, numpy order
        float w1 = 1.0f / (d1  + 1e-8f);
        float w2 = 1.0f / (d2v + 1e-8f);
        const float sum = (w0 + w1) + w2;
        s_idx[pl * 3 + 0] = i0;
        s_idx[pl * 3 + 1] = i1;
        s_idx[pl * 3 + 2] = i2;
        s_w[pl * 3 + 0] = w0 / sum;
        s_w[pl * 3 + 1] = w1 / sum;
        s_w[pl * 3 + 2] = w2 / sum;
    }
    __syncthreads();

    // ---------------- phase 2: interpolate + concat ----------------
    // 32 groups of 32 lanes; group g handles rows g, g+32, ... (448 rows).
    // Class boundaries (256, 320) are multiples of 32 -> uniform branches.
    const int g  = tid >> 5;
    const int l  = tid & 31;
    const int p0 = 2 * l;

    auto clampi = [](int v) { return v < 0 ? 0 : (v > MM - 1 ? MM - 1 : v); };
    const int   ia0 = clampi(s_idx[p0 * 3 + 0]);
    const int   ia1 = clampi(s_idx[p0 * 3 + 1]);
    const int   ia2 = clampi(s_idx[p0 * 3 + 2]);
    const int   ib0 = clampi(s_idx[p0 * 3 + 3]);
    const int   ib1 = clampi(s_idx[p0 * 3 + 4]);
    const int   ib2 = clampi(s_idx[p0 * 3 + 5]);
    const float wa0 = s_w[p0 * 3 + 0], wa1 = s_w[p0 * 3 + 1], wa2 = s_w[p0 * 3 + 2];
    const float wb0 = s_w[p0 * 3 + 3], wb1 = s_w[p0 * 3 + 4], wb2 = s_w[p0 * 3 + 5];

    const size_t outT_base = (size_t)BB * (CF + CP) * NN;

    for (int it = 0; it < (CF + CP + CT) / 32; ++it) {
        const int row = it * 32 + g;
        if (row < CF) {
            const float* src = refF + ((size_t)b * CF + row) * MM;
            float* dst = out + ((size_t)b * (CF + CP) + row) * NN + n0;
            float2 pr;
            pr.x = (wa0 * src[ia0] + wa1 * src[ia1]) + wa2 * src[ia2];
            pr.y = (wb0 * src[ib0] + wb1 * src[ib1]) + wb2 * src[ib2];
            *reinterpret_cast<float2*>(dst + p0) = pr;
        } else if (row < CF + CP) {
            const float* src = pf + ((size_t)b * CP + (row - CF)) * NN + n0;
            float* dst = out + ((size_t)b * (CF + CP) + row) * NN + n0;
            *reinterpret_cast<float2*>(dst + p0) =
                *reinterpret_cast<const float2*>(src + p0);
        } else {
            const int tr = row - (CF + CP);
            const float* src = refT + ((size_t)b * CT + tr) * MM;
            float* dst = out + outT_base + ((size_t)b * CT + tr) * NN + n0;
            float2 pr;
            pr.x = (wa0 * src[ia0] + wa1 * src[ia1]) + wa2 * src[ia2];
            pr.y = (wb0 * src[ib0] + wb1 * src[ib1]) + wb2 * src[ib2];
            *reinterpret_cast<float2*>(dst + p0) = pr;
        }
    }
}

extern "C" void kernel_launch(void* const* d_in, const int* in_sizes, int n_in,
                              void* d_out, int out_size, void* d_ws, size_t ws_size,
                              hipStream_t stream) {
    const float* coords     = (const float*)d_in[0];
    const float* ref_coords = (const float*)d_in[1];
    const float* refF       = (const float*)d_in[2];
    const float* refT       = (const float*)d_in[3];
    const float* pf         = (const float*)d_in[4];
    float* out = (float*)d_out;

    hipLaunchKernelGGL(fp_fused_kernel, dim3(NN / NPB, BB), dim3(TPB), 0, stream,
                       coords, ref_coords, refF, refT, pf, out);
}

// Round 10
// 217.150 us; speedup vs baseline: 1.3737x; 1.2138x over previous
//
#include <hip/hip_runtime.h>
#include <cstdint>

#define BB 2
#define NN 16384
#define MM 4096
#define CF 256
#define CT 128
#define CP 64
#define NPB 64      // query points per block (grid 512 -> staging FETCH low)
#define CHUNK 2048  // ref points staged in LDS per pass (32 KB)
#define TPB 512     // proven best shape (round 7: 167 us)

// All-FP32 monolithic kernel — round-7 proven structure with two bit-exact
// per-pair instruction reductions:
//  (a) refs staged as (2x, 2y, 2z, rr): fl(cx*(2rx)) = 2*fl(cx*rx) and
//      fl(2a+2b) = 2*fl(a+b) exactly (pure exponent shift, no denormals at
//      N(0,1) magnitudes) -> dd = (cc+rr) - dot2 matches numpy bit-for-bit
//      while saving the (t+t) add.
//  (b) top-3 VALUE updates via min/med3 (exact selection, 3 instrs) instead
//      of cmp+cndmask chains; INDEX updates keep strict-< compares so exact
//      ties still keep the first-seen (= lower j, ascending scan) neighbor.
// Phase 2 unchanged from round 7.
__global__ __launch_bounds__(TPB, 4) void fp_fused_kernel(
    const float* __restrict__ coords,      // [B,N,3]
    const float* __restrict__ ref_coords,  // [B,M,3]
    const float* __restrict__ refF,        // [B,256,M]
    const float* __restrict__ refT,        // [B,128,M]
    const float* __restrict__ pf,          // [B,64,N]
    float* __restrict__ out)               // [B,320,N] ++ [B,128,N]
{
#pragma clang fp contract(off)
    __shared__ float4 refs[CHUNK];      // 32 KB (2x, 2y, 2z, rr)
    __shared__ int    s_idx[NPB * 3];
    __shared__ float  s_w[NPB * 3];

    const int tid = threadIdx.x;
    const int b   = blockIdx.y;
    const int n0  = blockIdx.x * NPB;

    // ---------------- phase 1: 3-NN, 8 lanes per query point ----------------
    const int pl = tid >> 3;            // point-in-block 0..63
    const int s  = tid & 7;             // sub-lane 0..7
    const int n  = n0 + pl;

    const float* cp = coords + ((size_t)b * NN + n) * 3;
    const float cx = cp[0];
    const float cy = cp[1];
    const float cz = cp[2];
    const float cc = (cx * cx + cy * cy) + cz * cz;   // numpy sum order

    float d0 = INFINITY, d1 = INFINITY, d2v = INFINITY;
    int   i0 = 0, i1 = 0, i2 = 0;       // benign fallbacks (no sentinels)

    const float* rc = ref_coords + (size_t)b * MM * 3;

    for (int ch = 0; ch < MM / CHUNK; ++ch) {
        __syncthreads();                 // refs[] reuse guard
        for (int e = tid; e < CHUNK; e += TPB) {
            const int j = ch * CHUNK + e;
            const float x = rc[3 * j + 0];
            const float y = rc[3 * j + 1];
            const float z = rc[3 * j + 2];
            // rr from ORIGINAL coords (numpy order); xyz pre-doubled (exact)
            refs[e] = make_float4(x + x, y + y, z + z, (x * x + y * y) + z * z);
        }
        __syncthreads();

        // lane scans e = s, s+8, ... ascending -> strict '<' keeps lowest idx
        #pragma unroll 4
        for (int it = 0; it < CHUNK / 8; ++it) {
            const int e = s + (it << 3);
            const float4 r = refs[e];
            // dot2 == 2*((cx*rx + cy*ry) + cz*rz) bit-exactly (see header)
            const float dot2 = (cx * r.x + cy * r.y) + cz * r.z;
            const float dd   = (cc + r.w) - dot2;        // == numpy d2
            const int j = ch * CHUNK + e;

            // index network: strict < (ties keep first-seen = lower j)
            const bool l2 = dd < d2v;
            const bool l1 = dd < d1;
            const bool l0 = dd < d0;
            i2 = l2 ? (l1 ? i1 : j) : i2;
            i1 = l1 ? (l0 ? i0 : j) : i1;
            i0 = l0 ? j : i0;
            // value network: exact selection via min/med3 (old values!)
            const float n2 = __builtin_amdgcn_fmed3f(dd, d1, d2v);
            const float n1 = __builtin_amdgcn_fmed3f(dd, d0, d1);
            const float n0v = fminf(dd, d0);
            d2v = n2; d1 = n1; d0 = n0v;
        }
    }

    // lexicographic (d, idx) insert: lower index wins exact ties (stable top_k)
    auto ins = [&](float e, int f) {
        const bool l2 = (e < d2v) || (e == d2v && f < i2);
        const bool l1 = (e < d1)  || (e == d1  && f < i1);
        const bool l0 = (e < d0)  || (e == d0  && f < i0);
        d2v = l2 ? (l1 ? d1 : e) : d2v;  i2 = l2 ? (l1 ? i1 : f) : i2;
        d1  = l1 ? (l0 ? d0 : e) : d1;   i1 = l1 ? (l0 ? i0 : f) : i1;
        d0  = l0 ? e : d0;               i0 = l0 ? f : i0;
    };

    // butterfly across the 8 sub-lanes (xor<8 stays in-group, in-wave)
    for (int off = 1; off < 8; off <<= 1) {
        const float e0 = __shfl_xor(d0,  off, 64);
        const float e1 = __shfl_xor(d1,  off, 64);
        const float e2 = __shfl_xor(d2v, off, 64);
        const int   f0 = __shfl_xor(i0,  off, 64);
        const int   f1 = __shfl_xor(i1,  off, 64);
        const int   f2 = __shfl_xor(i2,  off, 64);
        ins(e0, f0);
        ins(e1, f1);
        ins(e2, f2);
    }

    if (s == 0) {
        float w0 = 1.0f / (d0  + 1e-8f);     // IEEE divs, numpy order
        float w1 = 1.0f / (d1  + 1e-8f);
        float w2 = 1.0f / (d2v + 1e-8f);
        const float sum = (w0 + w1) + w2;
        s_idx[pl * 3 + 0] = i0;
        s_idx[pl * 3 + 1] = i1;
        s_idx[pl * 3 + 2] = i2;
        s_w[pl * 3 + 0] = w0 / sum;
        s_w[pl * 3 + 1] = w1 / sum;
        s_w[pl * 3 + 2] = w2 / sum;
    }
    __syncthreads();

    // ---------------- phase 2: interpolate + concat ----------------
    // 16 groups of 32 lanes; group g handles rows g, g+16, ... (448 rows).
    // Class boundaries (256, 320) are multiples of 16 -> uniform branches.
    const int g  = tid >> 5;
    const int l  = tid & 31;
    const int p0 = 2 * l;

    auto clampi = [](int v) { return v < 0 ? 0 : (v > MM - 1 ? MM - 1 : v); };
    const int   ia0 = clampi(s_idx[p0 * 3 + 0]);
    const int   ia1 = clampi(s_idx[p0 * 3 + 1]);
    const int   ia2 = clampi(s_idx[p0 * 3 + 2]);
    const int   ib0 = clampi(s_idx[p0 * 3 + 3]);
    const int   ib1 = clampi(s_idx[p0 * 3 + 4]);
    const int   ib2 = clampi(s_idx[p0 * 3 + 5]);
    const float wa0 = s_w[p0 * 3 + 0], wa1 = s_w[p0 * 3 + 1], wa2 = s_w[p0 * 3 + 2];
    const float wb0 = s_w[p0 * 3 + 3], wb1 = s_w[p0 * 3 + 4], wb2 = s_w[p0 * 3 + 5];

    const size_t outT_base = (size_t)BB * (CF + CP) * NN;

    for (int it = 0; it < (CF + CP + CT) / 16; ++it) {
        const int row = it * 16 + g;
        if (row < CF) {
            const float* src = refF + ((size_t)b * CF + row) * MM;
            float* dst = out + ((size_t)b * (CF + CP) + row) * NN + n0;
            float2 pr;
            pr.x = (wa0 * src[ia0] + wa1 * src[ia1]) + wa2 * src[ia2];
            pr.y = (wb0 * src[ib0] + wb1 * src[ib1]) + wb2 * src[ib2];
            *reinterpret_cast<float2*>(dst + p0) = pr;
        } else if (row < CF + CP) {
            const float* src = pf + ((size_t)b * CP + (row - CF)) * NN + n0;
            float* dst = out + ((size_t)b * (CF + CP) + row) * NN + n0;
            *reinterpret_cast<float2*>(dst + p0) =
                *reinterpret_cast<const float2*>(src + p0);
        } else {
            const int tr = row - (CF + CP);
            const float* src = refT + ((size_t)b * CT + tr) * MM;
            float* dst = out + outT_base + ((size_t)b * CT + tr) * NN + n0;
            float2 pr;
            pr.x = (wa0 * src[ia0] + wa1 * src[ia1]) + wa2 * src[ia2];
            pr.y = (wb0 * src[ib0] + wb1 * src[ib1]) + wb2 * src[ib2];
            *reinterpret_cast<float2*>(dst + p0) = pr;
        }
    }
}

extern "C" void kernel_launch(void* const* d_in, const int* in_sizes, int n_in,
                              void* d_out, int out_size, void* d_ws, size_t ws_size,
                              hipStream_t stream) {
    const float* coords     = (const float*)d_in[0];
    const float* ref_coords = (const float*)d_in[1];
    const float* refF       = (const float*)d_in[2];
    const float* refT       = (const float*)d_in[3];
    const float* pf         = (const float*)d_in[4];
    float* out = (float*)d_out;

    hipLaunchKernelGGL(fp_fused_kernel, dim3(NN / NPB, BB), dim3(TPB), 0, stream,
                       coords, ref_coords, refF, refT, pf, out);
}